// Round 11
// baseline (171.981 us; speedup 1.0000x reference)
//
#include <hip/hip_runtime.h>

// SparseMCFModel — output `flow` depends ONLY on demands, edge_row, edge_col.
// w_e = 1/deg(row_e) exactly (softmax over identical logits per segment) -> the
// GAT/GRU/decoder pipeline is dead code. Since w depends on row only:
//   flow_j[e] = V_j[row_e],
//   V_1[v] = relu(d[v])/deg[v],
//   V_j[v] = (relu(d[v]) + sum_{e:col=v} V_{j-1}[row_e]) / deg[v],  j=2..10
//   out[e] = V_10[row_e].
//
// r10 lesson: the global barrier costs ~1.5-3 us and SCALES with block count;
// 11 barriers was ~1/3 of the kernel. This round: DATAFLOW. Ten level buffers
// pre-poisoned to 0xFFFFFFFF (NaN — computed V values are finite nonnegative,
// collision impossible). Publishing V_j[v] = ONE relaxed agent-scope 4B store
// of the value; consumers spin until word != sentinel. Single-word publish =
// value is the signal = no fences, no barriers in the iteration phase.
// Deadlock-free: level DAG is acyclic, all 256 blocks resident, intra-wave
// deps satisfied by program order (publish j-1 precedes any spin at j).
// Only ONE global barrier remains (after the deg histogram — a true global
// reduction). Barrier: zero-cache-op relaxed monotone counter (r6-r10).

#define N_NODES 20000
#define N_EDGES 200000
#define FLOW_ITERS 10
#define NBLK 256
#define NTHR 256
#define NTOT (NBLK * NTHR)                 // 65536
#define EPT ((N_EDGES + NTOT - 1) / NTOT)  // 4 edges/thread (build + final)
#define NPB 79                             // nodes per block (256*79 = 20224)
#define CAP 24                             // padded in-edge slots per node
#define SLOTS NTOT                         // slot space: bx*NTHR + tx
#define OFL_MAX 4096
#define NP1 (N_NODES + 1)
#define SENT 0xFFFFFFFFu

__device__ __forceinline__ float ld_coh(const float* p) {
    return __hip_atomic_load(p, __ATOMIC_RELAXED, __HIP_MEMORY_SCOPE_AGENT);
}
__device__ __forceinline__ int ld_coh_i(const int* p) {
    return __hip_atomic_load(p, __ATOMIC_RELAXED, __HIP_MEMORY_SCOPE_AGENT);
}
__device__ __forceinline__ void st_coh(float* p, float v) {
    __hip_atomic_store(p, v, __ATOMIC_RELAXED, __HIP_MEMORY_SCOPE_AGENT);
}
__device__ __forceinline__ void st_coh_i(int* p, int v) {
    __hip_atomic_store(p, v, __ATOMIC_RELAXED, __HIP_MEMORY_SCOPE_AGENT);
}

// Spin until the published word is not the sentinel; the loaded value IS the
// payload (single-word dataflow, no ordering needed).
__device__ __forceinline__ float spinld(const float* p) {
    float x = ld_coh(p);
    while (__float_as_uint(x) == SENT) {
        __builtin_amdgcn_s_sleep(1);
        x = ld_coh(p);
    }
    return x;
}

// Zero-cache-op monotone barrier (validated r6-r10).
__device__ __forceinline__ void gbar(int* cnt, int target) {
    __syncthreads();
    if (threadIdx.x == 0) {
        __hip_atomic_fetch_add(cnt, 1, __ATOMIC_RELAXED, __HIP_MEMORY_SCOPE_AGENT);
        while (__hip_atomic_load(cnt, __ATOMIC_RELAXED, __HIP_MEMORY_SCOPE_AGENT) < target)
            __builtin_amdgcn_s_sleep(2);
    }
    __syncthreads();
}

__global__ __launch_bounds__(NTHR)
void mcf_fused(const float* __restrict__ demands,
               const int* __restrict__ edge_row,
               const int* __restrict__ edge_col,
               float* __restrict__ out,
               int* __restrict__ deg,       // [N]   zeroed by memset
               int* __restrict__ fill,      // [N]   zeroed by memset
               float* __restrict__ Vbase,   // [10*NP1], poisoned 0xFF by memset
               int* __restrict__ pcsc,      // [CAP*SLOTS], [k*SLOTS + slot(v)]
               int* __restrict__ ofl_cnt,   // [1]   zeroed by memset
               int* __restrict__ ofl_v,     // [OFL_MAX]
               int* __restrict__ ofl_row,   // [OFL_MAX]
               int* __restrict__ barcnt)    // [1]   zeroed by memset
{
    const int tid = blockIdx.x * NTHR + threadIdx.x;

    // publish the zero sentinels for dummy slots (levels 1..10); readers spin
    // until non-sentinel, so this tiny cross-block race is benign.
    if (tid < FLOW_ITERS) st_coh(&Vbase[tid * NP1 + N_NODES], 0.0f);

    // ---- Phase B: deg histogram + slot-permuted CSC placement (one pass) ----
    int rowr[EPT];
    #pragma unroll
    for (int i = 0; i < EPT; ++i) {
        int e = tid + i * NTOT;
        rowr[i] = N_NODES;
        if (e < N_EDGES) {
            int r = edge_row[e], c = edge_col[e];
            rowr[i] = r;
            __hip_atomic_fetch_add(&deg[r], 1, __ATOMIC_RELAXED, __HIP_MEMORY_SCOPE_AGENT);
            int idx = __hip_atomic_fetch_add(&fill[c], 1,
                                             __ATOMIC_RELAXED, __HIP_MEMORY_SCOPE_AGENT);
            int slot = (c / NPB) * NTHR + (c % NPB);   // owner (block, thread)
            if (idx < CAP) {
                st_coh_i(&pcsc[idx * SLOTS + slot], r);
            } else {
                int o = __hip_atomic_fetch_add(ofl_cnt, 1,
                                               __ATOMIC_RELAXED, __HIP_MEMORY_SCOPE_AGENT);
                if (o < OFL_MAX) { st_coh_i(&ofl_v[o], c); st_coh_i(&ofl_row[o], r); }
            }
        }
    }
    gbar(barcnt, NBLK);   // the ONE barrier: deg/fill/pcsc complete after this

    // ---- Owner setup (coalesced pcsc reads) + publish V_1 ----
    const int tx = threadIdx.x;
    const int v  = blockIdx.x * NPB + tx;
    const bool active = (tx < NPB) && (v < N_NODES);
    float dposv = 0.0f, invd = 0.0f;
    int   cnt = 0, ocnt = 0;
    int   er[CAP];
    if (active) {
        dposv  = fmaxf(demands[v], 0.0f);
        int dv = ld_coh_i(&deg[v]);
        invd   = (dv > 0) ? (1.0f / (float)dv) : 0.0f;   // V[v] unread if deg==0
        cnt    = min(ld_coh_i(&fill[v]), CAP);
        ocnt   = ld_coh_i(ofl_cnt);                      // expected 0
        const int slot = blockIdx.x * NTHR + tx;         // lane-consecutive
        #pragma unroll
        for (int k = 0; k < CAP; ++k) {
            int r = pcsc[k * SLOTS + slot];   // plain, coalesced; lines never
            er[k] = (k < cnt) ? r : N_NODES;  // cached stale (written via st_coh)
        }
        st_coh(&Vbase[0 * NP1 + v], dposv * invd);       // publish V_1
    }

    // ---- Levels 2..10: spin-gather deps, publish own value. NO barriers. ----
    #pragma unroll 1
    for (int j = 2; j <= FLOW_ITERS; ++j) {
        const float* Vp = &Vbase[(j - 2) * NP1];
        float*       Vn = &Vbase[(j - 1) * NP1];
        if (active) {
            float acc = dposv;
            #pragma unroll
            for (int s = 0; s < CAP; ++s) acc += spinld(&Vp[er[s]]);
            if (ocnt > 0) {                     // exactness fallback, ~never
                for (int o = 0; o < ocnt && o < OFL_MAX; ++o)
                    if (ld_coh_i(&ofl_v[o]) == v)
                        acc += spinld(&Vp[ld_coh_i(&ofl_row[o])]);
            }
            st_coh(&Vn[v], acc * invd);         // publish V_j (value = signal)
        }
    }

    // ---- out[e] = V_10[row_e]; spin until published; coalesced stores ----
    const float* V10 = &Vbase[(FLOW_ITERS - 1) * NP1];
    #pragma unroll
    for (int i = 0; i < EPT; ++i) {
        int e = tid + i * NTOT;
        if (e < N_EDGES) out[e] = spinld(&V10[rowr[i]]);
    }
}

extern "C" void kernel_launch(void* const* d_in, const int* in_sizes, int n_in,
                              void* d_out, int out_size, void* d_ws, size_t ws_size,
                              hipStream_t stream) {
    const float* demands  = (const float*)d_in[1];
    const int*   edge_row = (const int*)d_in[2];
    const int*   edge_col = (const int*)d_in[3];
    float*       out      = (float*)d_out;

    char* ws = (char*)d_ws;
    auto take = [&](size_t bytes) {
        void* p = (void*)ws;
        ws += (bytes + 127) & ~size_t(127);
        return p;
    };
    // ---- zero zone (one 0x00 memset) ----
    char* zone0 = ws;
    int*   deg     = (int*)  take(N_NODES * 4);
    int*   fill    = (int*)  take(N_NODES * 4);
    int*   ofl_cnt = (int*)  take(4);
    int*   barcnt  = (int*)  take(4);
    size_t zone0_bytes = (size_t)(ws - zone0);
    // ---- sentinel zone (one 0xFF memset) ----
    char* zone1 = ws;
    float* Vbase   = (float*)take((size_t)FLOW_ITERS * NP1 * 4);
    size_t zone1_bytes = (size_t)(ws - zone1);
    // ---- uninitialized zone ----
    int*   pcsc    = (int*)  take((size_t)CAP * SLOTS * 4);
    int*   ofl_v   = (int*)  take(OFL_MAX * 4);
    int*   ofl_row = (int*)  take(OFL_MAX * 4);

    hipMemsetAsync(zone0, 0x00, zone0_bytes, stream);
    hipMemsetAsync(zone1, 0xFF, zone1_bytes, stream);
    mcf_fused<<<NBLK, NTHR, 0, stream>>>(demands, edge_row, edge_col, out,
                                         deg, fill, Vbase, pcsc,
                                         ofl_cnt, ofl_v, ofl_row, barcnt);
}

// Round 12
// 140.621 us; speedup vs baseline: 1.2230x; 1.2230x over previous
//
#include <hip/hip_runtime.h>

// SparseMCFModel — output `flow` depends ONLY on demands, edge_row, edge_col.
// w_e = 1/deg(row_e) exactly (softmax over identical logits per segment) -> the
// GAT/GRU/decoder pipeline is dead code. Since w depends on row only:
//   flow_j[e] = V_j[row_e],
//   V_1[v] = relu(d[v])/deg[v],
//   V_j[v] = (relu(d[v]) + sum_{e:col=v} V_{j-1}[row_e]) / deg[v],  j=2..10
//   out[e] = V_10[row_e].
//
// Config model from r9/r10/r11: work ~64us is config-independent; barrier
// ~1.2us @128 blocks vs ~3us @256; dataflow cascade == barrier cost (no win).
// So: r9 skeleton (128x512 + zero-cache-op relaxed monotone barriers) and cut
// the WORK: (1) pcsc slot-major [slot*CAP+k] -> a column's <=24 entries hit 2
// cache lines (k-major hit 10 pages) => scattered write-back 12.8->~2.5 MB;
// (2) memset replaces Phase A (+1 fewer barrier); (3) CAP 24.

#define N_NODES 20000
#define N_EDGES 200000
#define FLOW_ITERS 10
#define NBLK 128
#define NTHR 512
#define NTOT (NBLK * NTHR)                 // 65536
#define EPT ((N_EDGES + NTOT - 1) / NTOT)  // 4 edges/thread (build + final)
#define NPB 157                            // nodes per block (128*157 = 20096)
#define CAP 24                             // padded in-edge slots per node
#define SLOTS NTOT                         // slot space: bx*NTHR + tx
#define OFL_MAX 4096
#define NP1 (N_NODES + 1)

__device__ __forceinline__ float ld_coh(const float* p) {
    return __hip_atomic_load(p, __ATOMIC_RELAXED, __HIP_MEMORY_SCOPE_AGENT);
}
__device__ __forceinline__ int ld_coh_i(const int* p) {
    return __hip_atomic_load(p, __ATOMIC_RELAXED, __HIP_MEMORY_SCOPE_AGENT);
}
__device__ __forceinline__ void st_coh(float* p, float v) {
    __hip_atomic_store(p, v, __ATOMIC_RELAXED, __HIP_MEMORY_SCOPE_AGENT);
}
__device__ __forceinline__ void st_coh_i(int* p, int v) {
    __hip_atomic_store(p, v, __ATOMIC_RELAXED, __HIP_MEMORY_SCOPE_AGENT);
}

// Zero-cache-op monotone barrier (validated r6-r11): __syncthreads drains
// vmcnt per wave before s_barrier, so coherent-point writes are globally
// visible before the relaxed arrive; all post-barrier cross-block reads use
// coherent-point ops or touch lines never cached stale.
__device__ __forceinline__ void gbar(int* cnt, int target) {
    __syncthreads();
    if (threadIdx.x == 0) {
        __hip_atomic_fetch_add(cnt, 1, __ATOMIC_RELAXED, __HIP_MEMORY_SCOPE_AGENT);
        while (__hip_atomic_load(cnt, __ATOMIC_RELAXED, __HIP_MEMORY_SCOPE_AGENT) < target)
            __builtin_amdgcn_s_sleep(2);
    }
    __syncthreads();
}

__global__ __launch_bounds__(NTHR)
void mcf_fused(const float* __restrict__ demands,
               const int* __restrict__ edge_row,
               const int* __restrict__ edge_col,
               float* __restrict__ out,
               int* __restrict__ deg,       // [N]   zeroed by memset
               int* __restrict__ fill,      // [N]   zeroed by memset
               float* __restrict__ V0,      // [N+1] zeroed by memset (sentinel)
               float* __restrict__ V1b,     // [N+1] zeroed by memset (sentinel)
               int* __restrict__ pcsc,      // [SLOTS*CAP], [slot(v)*CAP + k]
               int* __restrict__ ofl_cnt,   // [1]   zeroed by memset
               int* __restrict__ ofl_v,     // [OFL_MAX]
               int* __restrict__ ofl_row,   // [OFL_MAX]
               int* __restrict__ barcnt)    // [1]   zeroed by memset
{
    const int tid = blockIdx.x * NTHR + threadIdx.x;
    int bar = 0;

    // ---- Build: deg histogram + slot-major CSC placement (one pass) ----
    int rowr[EPT];
    #pragma unroll
    for (int i = 0; i < EPT; ++i) {
        int e = tid + i * NTOT;
        rowr[i] = N_NODES;
        if (e < N_EDGES) {
            int r = edge_row[e], c = edge_col[e];
            rowr[i] = r;
            __hip_atomic_fetch_add(&deg[r], 1, __ATOMIC_RELAXED, __HIP_MEMORY_SCOPE_AGENT);
            int idx = __hip_atomic_fetch_add(&fill[c], 1,
                                             __ATOMIC_RELAXED, __HIP_MEMORY_SCOPE_AGENT);
            int slot = (c / NPB) * NTHR + (c % NPB);   // owner (block, thread)
            if (idx < CAP) {
                st_coh_i(&pcsc[slot * CAP + idx], r);  // 2-line-local per col
            } else {
                int o = __hip_atomic_fetch_add(ofl_cnt, 1,
                                               __ATOMIC_RELAXED, __HIP_MEMORY_SCOPE_AGENT);
                if (o < OFL_MAX) { st_coh_i(&ofl_v[o], c); st_coh_i(&ofl_row[o], r); }
            }
        }
    }
    gbar(barcnt, NBLK * (++bar));

    // ---- Owner setup: per-thread contiguous 96B pcsc run (L1-absorbed) ----
    const int tx = threadIdx.x;
    const int v  = blockIdx.x * NPB + tx;
    const bool active = (tx < NPB) && (v < N_NODES);
    float dposv = 0.0f, invd = 0.0f;
    int   cnt = 0, ocnt = 0;
    int   er[CAP];
    if (active) {
        dposv  = fmaxf(demands[v], 0.0f);
        int dv = ld_coh_i(&deg[v]);
        invd   = (dv > 0) ? (1.0f / (float)dv) : 0.0f;   // V[v] unread if deg==0
        cnt    = min(ld_coh_i(&fill[v]), CAP);
        ocnt   = ld_coh_i(ofl_cnt);                      // expected 0
        const int slot = blockIdx.x * NTHR + tx;
        #pragma unroll
        for (int k = 0; k < CAP; ++k) {
            int r = pcsc[slot * CAP + k];     // plain; lines never cached stale
            er[k] = (k < cnt) ? r : N_NODES;  // dummy -> zero sentinel
        }
        st_coh(&V0[v], dposv * invd);         // publish V_1, coalesced
    }
    gbar(barcnt, NBLK * (++bar));

    // ---- 9 iterations: CAP independent random coherent gathers per node ----
    #pragma unroll 1
    for (int j = 2; j <= FLOW_ITERS; ++j) {
        const float* Vp = (j & 1) ? V1b : V0;   // j even: read V0, write V1b
        float*       Vn = (j & 1) ? V0 : V1b;
        if (active) {
            float sk[CAP];
            #pragma unroll
            for (int s = 0; s < CAP; ++s) sk[s] = ld_coh(&Vp[er[s]]);
            float acc = dposv;
            #pragma unroll
            for (int s = 0; s < CAP; ++s) acc += sk[s];
            if (ocnt > 0) {                     // exactness fallback, ~never
                for (int o = 0; o < ocnt && o < OFL_MAX; ++o)
                    if (ld_coh_i(&ofl_v[o]) == v)
                        acc += ld_coh(&Vp[ld_coh_i(&ofl_row[o])]);
            }
            st_coh(&Vn[v], acc * invd);         // coalesced publish
        }
        gbar(barcnt, NBLK * (++bar));
    }

    // ---- out[e] = V_10[row_e]  (j=10 wrote V1b); coalesced stores ----
    #pragma unroll
    for (int i = 0; i < EPT; ++i) {
        int e = tid + i * NTOT;
        if (e < N_EDGES) out[e] = ld_coh(&V1b[rowr[i]]);
    }
}

extern "C" void kernel_launch(void* const* d_in, const int* in_sizes, int n_in,
                              void* d_out, int out_size, void* d_ws, size_t ws_size,
                              hipStream_t stream) {
    const float* demands  = (const float*)d_in[1];
    const int*   edge_row = (const int*)d_in[2];
    const int*   edge_col = (const int*)d_in[3];
    float*       out      = (float*)d_out;

    char* ws = (char*)d_ws;
    auto take = [&](size_t bytes) {
        void* p = (void*)ws;
        ws += (bytes + 127) & ~size_t(127);
        return p;
    };
    // ---- zero zone (one 0x00 memset) ----
    char* zone0 = ws;
    int*   deg     = (int*)  take(N_NODES * 4);
    int*   fill    = (int*)  take(N_NODES * 4);
    float* V0      = (float*)take(NP1 * 4);
    float* V1b     = (float*)take(NP1 * 4);
    int*   ofl_cnt = (int*)  take(4);
    int*   barcnt  = (int*)  take(4);
    size_t zone0_bytes = (size_t)(ws - zone0);
    // ---- uninitialized zone ----
    int*   pcsc    = (int*)  take((size_t)SLOTS * CAP * 4);
    int*   ofl_v   = (int*)  take(OFL_MAX * 4);
    int*   ofl_row = (int*)  take(OFL_MAX * 4);

    hipMemsetAsync(zone0, 0x00, zone0_bytes, stream);
    mcf_fused<<<NBLK, NTHR, 0, stream>>>(demands, edge_row, edge_col, out,
                                         deg, fill, V0, V1b, pcsc,
                                         ofl_cnt, ofl_v, ofl_row, barcnt);
}